// Round 7
// baseline (131.855 us; speedup 1.0000x reference)
//
#include <hip/hip_runtime.h>
#include <hip/hip_bf16.h>
#include <stdint.h>
#include <stddef.h>

#define BATCH 4096
#define INF   1024
#define OUTF  1024
#define KDIM  8192            // 1024 in-features * 8 spline bases
#define KS    4               // split-K factor
#define KSL   (KDIM / KS)     // 2048 per slice
#define BK    32
#define NT    (KSL / BK)      // 64 K-tiles per block

typedef __attribute__((ext_vector_type(8))) short  short8;
typedef __attribute__((ext_vector_type(4))) float  f32x4;

__device__ constexpr float knot(int j) { return (float)(j - 3) * 0.4f - 1.0f; }

// ---------------------------------------------------------------------------
// Kernel 1: B-spline bases. One thread per (b,i); writes 8 bf16 (16 B).
// ---------------------------------------------------------------------------
__global__ __launch_bounds__(256) void kan_bases(const float* __restrict__ x,
                                                 short8* __restrict__ A) {
    size_t idx = (size_t)blockIdx.x * 256 + threadIdx.x;
    float xv = x[idx];

    float b[11];
#pragma unroll
    for (int j = 0; j < 11; ++j)
        b[j] = (xv >= knot(j) && xv < knot(j + 1)) ? 1.0f : 0.0f;

#pragma unroll
    for (int k = 1; k <= 3; ++k) {
#pragma unroll
        for (int j = 0; j + k < 11; ++j) {
            float left  = (xv - knot(j))         * (1.0f / (knot(j + k)     - knot(j)));
            float right = (knot(j + k + 1) - xv) * (1.0f / (knot(j + k + 1) - knot(j + 1)));
            b[j] = left * b[j] + right * b[j + 1];
        }
    }

    union { short8 v; unsigned short u[8]; } pk;
#pragma unroll
    for (int g = 0; g < 8; ++g) {
        __hip_bfloat16 h = __float2bfloat16(b[g]);
        pk.u[g] = *reinterpret_cast<unsigned short*>(&h);
    }
    A[idx] = pk.v;
}

// ---------------------------------------------------------------------------
// Kernel 2: weight fp32 -> bf16 (B^T row-major over k = i*8+g already).
// ---------------------------------------------------------------------------
__global__ __launch_bounds__(256) void kan_wconv(const f32x4* __restrict__ w,
                                                 short8* __restrict__ Wb) {
    size_t idx = (size_t)blockIdx.x * 256 + threadIdx.x;
    f32x4 a = w[idx * 2];
    f32x4 c = w[idx * 2 + 1];
    float t[8] = {a[0], a[1], a[2], a[3], c[0], c[1], c[2], c[3]};
    union { short8 v; unsigned short u[8]; } pk;
#pragma unroll
    for (int g = 0; g < 8; ++g) {
        __hip_bfloat16 h = __float2bfloat16(t[g]);
        pk.u[g] = *reinterpret_cast<unsigned short*>(&h);
    }
    Wb[idx] = pk.v;
}

// ---------------------------------------------------------------------------
// Kernel 3: bf16 GEMM, 256x256 tile, BK=32, split-K=4, ring-4 LDS (128 KiB).
// 512 threads = 8 waves (2M x 4N), per-wave 128x64 (acc[8][4]).
// Distance-3 prefetch; ONE counted vmcnt(8) + ONE barrier per K-tile.
// BK=32 row stride (64 B) makes frag reads bank-conflict-free with a LINEAR
// layout (bank = 16*(lr&1) + 4*lk + {0..3}, 8 accesses/bank = b128 minimum),
// so no swizzle anywhere.
// mode 0: store split-K partials to P; mode 1: atomicAdd into pre-zeroed C.
// ---------------------------------------------------------------------------
__device__ __forceinline__ void gload16(const void* g, void* l) {
    __builtin_amdgcn_global_load_lds((const __attribute__((address_space(1))) void*)g,
                                     (__attribute__((address_space(3))) void*)l,
                                     16, 0, 0);
}

#define MFMA(a, b, c) __builtin_amdgcn_mfma_f32_16x16x32_bf16((a), (b), (c), 0, 0, 0)

__global__ __launch_bounds__(512, 2) void kan_gemm(const __hip_bfloat16* __restrict__ A,
                                                   const __hip_bfloat16* __restrict__ Bt,
                                                   float* __restrict__ out,
                                                   int mode) {
    __shared__ __hip_bfloat16 sA[4][256 * 32];   // 64 KiB ring
    __shared__ __hip_bfloat16 sB[4][256 * 32];   // 64 KiB ring

    const int tid  = threadIdx.x;
    const int orig = blockIdx.x;
    const int sb   = (orig & 7) * 32 + (orig >> 3);   // XCD chunk swizzle (256%8==0)
    const int bm   = sb >> 4;            // 0..15
    const int bn   = (sb >> 2) & 3;      // 0..3
    const int ks   = sb & 3;             // 0..3
    const int m0   = bm << 8;
    const int n0   = bn << 8;
    const int k0   = ks * KSL;

    // staging (linear): thread t, step r -> LDS elem r*4096 + t*8
    //   = row (r*128 + t>>2), col (t&3)*8.  Source matches exactly.
    const int srow = tid >> 2;                    // 0..127
    const int scol = (tid & 3) << 3;              // 0,8,16,24 elems
    const __hip_bfloat16* gA = A  + (size_t)(m0 + srow) * KDIM + k0 + scol;
    const __hip_bfloat16* gB = Bt + (size_t)(n0 + srow) * KDIM + k0 + scol;
    const int t8 = tid * 8;

#define GLA(slot, kt, r) gload16(gA + (size_t)(kt) * BK + (size_t)((r) * 128) * KDIM, \
                                 &sA[slot][(r) * 4096 + t8])
#define GLB(slot, kt, r) gload16(gB + (size_t)(kt) * BK + (size_t)((r) * 128) * KDIM, \
                                 &sB[slot][(r) * 4096 + t8])

    // compute: wave w -> rows [wr*128,+128), cols [wc*64,+64)
    const int w    = tid >> 6;
    const int lane = tid & 63;
    const int wr   = (w >> 2) & 1;       // 0..1
    const int wc   = w & 3;              // 0..3
    const int lr   = lane & 15;
    const int lk   = lane >> 4;          // 0..3
    const int kx   = lk << 3;            // elem col (linear)
    const int ar0  = (wr << 7) + lr;     // + fi*16
    const int br0  = (wc << 6) + lr;     // + fj*16

    f32x4 acc[8][4];
#pragma unroll
    for (int i = 0; i < 8; ++i)
#pragma unroll
        for (int j = 0; j < 4; ++j)
            acc[i][j] = (f32x4){0.0f, 0.0f, 0.0f, 0.0f};

    // --- prologue: stage tiles 0,1,2 (12 loads); wait tile 0 (oldest 4) ---
    GLA(0, 0, 0); GLA(0, 0, 1); GLB(0, 0, 0); GLB(0, 0, 1);
    GLA(1, 1, 0); GLA(1, 1, 1); GLB(1, 1, 0); GLB(1, 1, 1);
    GLA(2, 2, 0); GLA(2, 2, 1); GLB(2, 2, 0); GLB(2, 2, 1);
    asm volatile("s_waitcnt vmcnt(8)" ::: "memory");
    __builtin_amdgcn_s_barrier();

#pragma unroll 1
    for (int t = 0; t < NT; ++t) {
        const int s  = t & 3;
        const __hip_bfloat16* tA = &sA[s][0];
        const __hip_bfloat16* tB = &sB[s][0];

        // prefetch tile t+3 into slot (t+3)&3 (its readers finished at barrier t-1->t)
        if (t + 3 < NT) {
            const int s3 = (t + 3) & 3;
            GLA(s3, t + 3, 0); GLA(s3, t + 3, 1);
            GLB(s3, t + 3, 0); GLB(s3, t + 3, 1);
        }
        __builtin_amdgcn_sched_barrier(0);   // keep prefetch issue at phase top

        // body: plain reads + MFMAs; compiler pipelines via counted lgkmcnt
        short8 af[8], bf[4];
#pragma unroll
        for (int fi = 0; fi < 8; ++fi)
            af[fi] = *reinterpret_cast<const short8*>(tA + (ar0 + fi * 16) * BK + kx);
#pragma unroll
        for (int fj = 0; fj < 4; ++fj)
            bf[fj] = *reinterpret_cast<const short8*>(tB + (br0 + fj * 16) * BK + kx);
#pragma unroll
        for (int fi = 0; fi < 8; ++fi)
#pragma unroll
            for (int fj = 0; fj < 4; ++fj)
                acc[fi][fj] = MFMA(af[fi], bf[fj], acc[fi][fj]);

        // --- single boundary: tile t+1 landed; t+2,t+3 stay in flight ---
        const int rem = NT - 2 - t;
        if (rem >= 2)      asm volatile("s_waitcnt vmcnt(8)" ::: "memory");
        else if (rem == 1) asm volatile("s_waitcnt vmcnt(4)" ::: "memory");
        else               asm volatile("s_waitcnt vmcnt(0)" ::: "memory");
        __builtin_amdgcn_s_barrier();
    }
#undef GLA
#undef GLB

    // --- epilogue: C/D layout col = lane&15, row = (lane>>4)*4 + reg ---
    if (mode == 0) {
        float* P = out + (size_t)ks * BATCH * OUTF;
#pragma unroll
        for (int fi = 0; fi < 8; ++fi) {
#pragma unroll
            for (int fj = 0; fj < 4; ++fj) {
                float* cp = P + (size_t)(m0 + (wr << 7) + fi * 16 + lk * 4) * OUTF
                              + (n0 + (wc << 6) + fj * 16 + lr);
#pragma unroll
                for (int r = 0; r < 4; ++r)
                    cp[(size_t)r * OUTF] = acc[fi][fj][r];
            }
        }
    } else {
#pragma unroll
        for (int fi = 0; fi < 8; ++fi) {
#pragma unroll
            for (int fj = 0; fj < 4; ++fj) {
                float* cp = out + (size_t)(m0 + (wr << 7) + fi * 16 + lk * 4) * OUTF
                               + (n0 + (wc << 6) + fj * 16 + lr);
#pragma unroll
                for (int r = 0; r < 4; ++r)
                    atomicAdd(cp + (size_t)r * OUTF, acc[fi][fj][r]);
            }
        }
    }
}

// ---------------------------------------------------------------------------
// Kernel 4: split-K reduce  out = P0 + P1 + P2 + P3
// ---------------------------------------------------------------------------
__global__ __launch_bounds__(256) void kan_reduce(const f32x4* __restrict__ P,
                                                  f32x4* __restrict__ out) {
    size_t i = (size_t)blockIdx.x * 256 + threadIdx.x;   // 1M f32x4
    const size_t stride = (size_t)BATCH * OUTF / 4;
    out[i] = ((P[i] + P[i + stride]) + (P[i + 2 * stride] + P[i + 3 * stride]));
}

// ---------------------------------------------------------------------------
extern "C" void kernel_launch(void* const* d_in, const int* in_sizes, int n_in,
                              void* d_out, int out_size, void* d_ws, size_t ws_size,
                              hipStream_t stream) {
    const float* x = (const float*)d_in[0];       // (4096, 1024) fp32
    const float* w = (const float*)d_in[1];       // (1024, 1024, 8) fp32
    float* out = (float*)d_out;                   // (4096, 1024) fp32

    const size_t offW  = (size_t)BATCH * KDIM * 2;           // Abf: 64 MiB
    const size_t offP  = offW + (size_t)OUTF * KDIM * 2;     // Wbf: +16 MiB
    const size_t needP = offP + (size_t)KS * BATCH * OUTF * sizeof(float); // +64 MiB

    __hip_bfloat16* Abf = (__hip_bfloat16*)d_ws;
    __hip_bfloat16* Wbf = (__hip_bfloat16*)((char*)d_ws + offW);
    float*          P   = (float*)((char*)d_ws + offP);
    const bool partials = (ws_size >= needP);

    kan_bases<<<(BATCH * INF) / 256, 256, 0, stream>>>(x, (short8*)Abf);
    kan_wconv<<<(OUTF * KDIM / 8) / 256, 256, 0, stream>>>((const f32x4*)w, (short8*)Wbf);

    const int grid = (BATCH / 256) * (OUTF / 256) * KS;     // 256
    if (partials) {
        kan_gemm<<<grid, 512, 0, stream>>>(Abf, Wbf, P, 0);
        kan_reduce<<<(BATCH * OUTF / 4) / 256, 256, 0, stream>>>((const f32x4*)P, (f32x4*)out);
    } else {
        hipMemsetAsync(out, 0, (size_t)BATCH * OUTF * sizeof(float), stream);
        kan_gemm<<<grid, 512, 0, stream>>>(Abf, Wbf, out, 1);
    }
}

// Round 8
// 120.483 us; speedup vs baseline: 1.0944x; 1.0944x over previous
//
#include <hip/hip_runtime.h>
#include <hip/hip_bf16.h>
#include <stdint.h>
#include <stddef.h>

#define BATCH 4096
#define INF   1024
#define OUTF  1024
#define KDIM  8192            // 1024 in-features * 8 spline bases
#define KS    4               // split-K factor
#define KSL   (KDIM / KS)     // 2048 per slice
#define BK    32
#define NT    (KSL / BK)      // 64 K-tiles per block

typedef __attribute__((ext_vector_type(8)))  short  short8;
typedef __attribute__((ext_vector_type(4)))  float  f32x4;
typedef __attribute__((ext_vector_type(16))) float  f32x16;

__device__ constexpr float knot(int j) { return (float)(j - 3) * 0.4f - 1.0f; }

// ---------------------------------------------------------------------------
// Kernel 1: B-spline bases. One thread per (b,i); writes 8 bf16 (16 B).
// ---------------------------------------------------------------------------
__global__ __launch_bounds__(256) void kan_bases(const float* __restrict__ x,
                                                 short8* __restrict__ A) {
    size_t idx = (size_t)blockIdx.x * 256 + threadIdx.x;
    float xv = x[idx];

    float b[11];
#pragma unroll
    for (int j = 0; j < 11; ++j)
        b[j] = (xv >= knot(j) && xv < knot(j + 1)) ? 1.0f : 0.0f;

#pragma unroll
    for (int k = 1; k <= 3; ++k) {
#pragma unroll
        for (int j = 0; j + k < 11; ++j) {
            float left  = (xv - knot(j))         * (1.0f / (knot(j + k)     - knot(j)));
            float right = (knot(j + k + 1) - xv) * (1.0f / (knot(j + k + 1) - knot(j + 1)));
            b[j] = left * b[j] + right * b[j + 1];
        }
    }

    union { short8 v; unsigned short u[8]; } pk;
#pragma unroll
    for (int g = 0; g < 8; ++g) {
        __hip_bfloat16 h = __float2bfloat16(b[g]);
        pk.u[g] = *reinterpret_cast<unsigned short*>(&h);
    }
    A[idx] = pk.v;
}

// ---------------------------------------------------------------------------
// Kernel 2: weight fp32 -> bf16 (B^T row-major over k = i*8+g already).
// ---------------------------------------------------------------------------
__global__ __launch_bounds__(256) void kan_wconv(const f32x4* __restrict__ w,
                                                 short8* __restrict__ Wb) {
    size_t idx = (size_t)blockIdx.x * 256 + threadIdx.x;
    f32x4 a = w[idx * 2];
    f32x4 c = w[idx * 2 + 1];
    float t[8] = {a[0], a[1], a[2], a[3], c[0], c[1], c[2], c[3]};
    union { short8 v; unsigned short u[8]; } pk;
#pragma unroll
    for (int g = 0; g < 8; ++g) {
        __hip_bfloat16 h = __float2bfloat16(t[g]);
        pk.u[g] = *reinterpret_cast<unsigned short*>(&h);
    }
    Wb[idx] = pk.v;
}

// ---------------------------------------------------------------------------
// Kernel 3: bf16 GEMM, 256x256 tile, BK=32, split-K=4, ring-4 LDS (128 KiB).
// 1024 threads = 16 waves (4M x 4N, 64x64 per wave) -> 4 waves/SIMD for
// latency hiding. mfma_f32_32x32x16_bf16 (4060 FLOP/cy/CU rate).
// Distance-3 prefetch; ONE counted vmcnt(4) + ONE barrier per K-tile.
// 4-slot XOR swizzle: LDS[row][slot] = G[row][slot ^ ((row>>1)&3)], applied
// to gload SOURCE and ds_read col (involution both sides); residual 2-way.
// mode 0: split-K partials to P; mode 1: atomicAdd into pre-zeroed C.
// ---------------------------------------------------------------------------
__device__ __forceinline__ void gload16(const void* g, void* l) {
    __builtin_amdgcn_global_load_lds((const __attribute__((address_space(1))) void*)g,
                                     (__attribute__((address_space(3))) void*)l,
                                     16, 0, 0);
}

#define MFMA32(a, b, c) __builtin_amdgcn_mfma_f32_32x32x16_bf16((a), (b), (c), 0, 0, 0)

__global__ __launch_bounds__(1024, 1) void kan_gemm(const __hip_bfloat16* __restrict__ A,
                                                    const __hip_bfloat16* __restrict__ Bt,
                                                    float* __restrict__ out,
                                                    int mode) {
    __shared__ __hip_bfloat16 sA[4][256 * 32];   // 64 KiB ring
    __shared__ __hip_bfloat16 sB[4][256 * 32];   // 64 KiB ring

    const int tid  = threadIdx.x;
    const int orig = blockIdx.x;
    const int sb   = (orig & 7) * 32 + (orig >> 3);   // XCD chunk swizzle (256%8==0)
    const int bm   = sb >> 4;            // 0..15
    const int bn   = (sb >> 2) & 3;      // 0..3
    const int ks   = sb & 3;             // 0..3
    const int m0   = bm << 8;
    const int n0   = bn << 8;
    const int k0   = ks * KSL;

    // staging: thread t -> LDS row (t>>2), 16B slot (t&3), linear dest t*16B.
    // source slot pre-swizzled by ((row>>1)&3) = ((t>>3)&3).
    const int srow = tid >> 2;                          // 0..255
    const int scol = (((tid & 3) ^ ((tid >> 3) & 3)) << 3);
    const __hip_bfloat16* gA = A  + (size_t)(m0 + srow) * KDIM + k0 + scol;
    const __hip_bfloat16* gB = Bt + (size_t)(n0 + srow) * KDIM + k0 + scol;
    const int t8 = tid * 8;

#define GLA(slot, kt) gload16(gA + (size_t)(kt) * BK, &sA[slot][t8])
#define GLB(slot, kt) gload16(gB + (size_t)(kt) * BK, &sB[slot][t8])

    // compute: wave w -> rows [ (w>>2)*64, +64 ), cols [ (w&3)*64, +64 )
    const int w    = tid >> 6;
    const int lane = tid & 63;
    const int wr   = w >> 2;             // 0..3
    const int wc   = w & 3;              // 0..3
    const int l31  = lane & 31;
    const int l5   = lane >> 5;          // 0..1
    const int swz  = (lane >> 1) & 3;    // == ((row>>1)&3) for row = base + l31
    const int ar0  = (wr << 6) + l31;    // + fi*32
    const int br0  = (wc << 6) + l31;    // + fj*32

    f32x16 acc00 = {}, acc01 = {}, acc10 = {}, acc11 = {};

    // --- prologue: stage tiles 0,1,2 (6 loads/thread); wait tile 0 ---
    GLA(0, 0); GLB(0, 0);
    GLA(1, 1); GLB(1, 1);
    GLA(2, 2); GLB(2, 2);
    asm volatile("s_waitcnt vmcnt(4)" ::: "memory");
    __builtin_amdgcn_s_barrier();

#pragma unroll 1
    for (int t = 0; t < NT; ++t) {
        const int s = t & 3;
        const __hip_bfloat16* tA = &sA[s][0];
        const __hip_bfloat16* tB = &sB[s][0];

        // prefetch tile t+3 into slot (t+3)&3 (readers done at barrier t-1->t)
        if (t + 3 < NT) {
            const int s3 = (t + 3) & 3;
            GLA(s3, t + 3); GLB(s3, t + 3);
        }
        __builtin_amdgcn_sched_barrier(0);   // pin prefetch issue at loop top

        // body: 2 kk-steps; per step 4 ds_read_b128 + 4 MFMA(32x32x16).
        // frag: row = base + (lane&31); k-slot = kk*2 + (lane>>5), XOR-swizzled.
#pragma unroll
        for (int kk = 0; kk < 2; ++kk) {
            const int sl = ((kk * 2 + l5) ^ swz) << 3;   // elem offset in row
            short8 a0 = *reinterpret_cast<const short8*>(tA + (ar0     ) * BK + sl);
            short8 a1 = *reinterpret_cast<const short8*>(tA + (ar0 + 32) * BK + sl);
            short8 b0 = *reinterpret_cast<const short8*>(tB + (br0     ) * BK + sl);
            short8 b1 = *reinterpret_cast<const short8*>(tB + (br0 + 32) * BK + sl);
            acc00 = MFMA32(a0, b0, acc00);
            acc01 = MFMA32(a0, b1, acc01);
            acc10 = MFMA32(a1, b0, acc10);
            acc11 = MFMA32(a1, b1, acc11);
        }

        // --- single boundary: tile t+1 landed; t+2,t+3 stay in flight ---
        const int rem = NT - 2 - t;
        if (rem >= 2)      asm volatile("s_waitcnt vmcnt(4)" ::: "memory");
        else if (rem == 1) asm volatile("s_waitcnt vmcnt(2)" ::: "memory");
        else               asm volatile("s_waitcnt vmcnt(0)" ::: "memory");
        __builtin_amdgcn_s_barrier();
    }
#undef GLA
#undef GLB

    // --- epilogue: 32x32 C/D layout: col = lane&31,
    //     row = (reg&3) + 8*(reg>>2) + 4*(lane>>5)  [m74/m101] ---
#define STORE_FRAG(accv, fi, fj)                                               \
    _Pragma("unroll")                                                          \
    for (int r = 0; r < 16; ++r) {                                             \
        int row = m0 + (wr << 6) + (fi) * 32 + (r & 3) + 8 * (r >> 2) + 4 * l5;\
        int col = n0 + (wc << 6) + (fj) * 32 + l31;                            \
        dst[(size_t)row * OUTF + col] = accv[r];                               \
    }
#define ATOM_FRAG(accv, fi, fj)                                                \
    _Pragma("unroll")                                                          \
    for (int r = 0; r < 16; ++r) {                                             \
        int row = m0 + (wr << 6) + (fi) * 32 + (r & 3) + 8 * (r >> 2) + 4 * l5;\
        int col = n0 + (wc << 6) + (fj) * 32 + l31;                            \
        atomicAdd(&out[(size_t)row * OUTF + col], accv[r]);                    \
    }

    if (mode == 0) {
        float* dst = out + (size_t)ks * BATCH * OUTF;
        STORE_FRAG(acc00, 0, 0);
        STORE_FRAG(acc01, 0, 1);
        STORE_FRAG(acc10, 1, 0);
        STORE_FRAG(acc11, 1, 1);
    } else {
        ATOM_FRAG(acc00, 0, 0);
        ATOM_FRAG(acc01, 0, 1);
        ATOM_FRAG(acc10, 1, 0);
        ATOM_FRAG(acc11, 1, 1);
    }
#undef STORE_FRAG
#undef ATOM_FRAG
}

// ---------------------------------------------------------------------------
// Kernel 4: split-K reduce  out = P0 + P1 + P2 + P3
// ---------------------------------------------------------------------------
__global__ __launch_bounds__(256) void kan_reduce(const f32x4* __restrict__ P,
                                                  f32x4* __restrict__ out) {
    size_t i = (size_t)blockIdx.x * 256 + threadIdx.x;   // 1M f32x4
    const size_t stride = (size_t)BATCH * OUTF / 4;
    out[i] = ((P[i] + P[i + stride]) + (P[i + 2 * stride] + P[i + 3 * stride]));
}

// ---------------------------------------------------------------------------
extern "C" void kernel_launch(void* const* d_in, const int* in_sizes, int n_in,
                              void* d_out, int out_size, void* d_ws, size_t ws_size,
                              hipStream_t stream) {
    const float* x = (const float*)d_in[0];       // (4096, 1024) fp32
    const float* w = (const float*)d_in[1];       // (1024, 1024, 8) fp32
    float* out = (float*)d_out;                   // (4096, 1024) fp32

    const size_t offW  = (size_t)BATCH * KDIM * 2;           // Abf: 64 MiB
    const size_t offP  = offW + (size_t)OUTF * KDIM * 2;     // Wbf: +16 MiB
    const size_t needP = offP + (size_t)KS * BATCH * OUTF * sizeof(float); // +64 MiB

    __hip_bfloat16* Abf = (__hip_bfloat16*)d_ws;
    __hip_bfloat16* Wbf = (__hip_bfloat16*)((char*)d_ws + offW);
    float*          P   = (float*)((char*)d_ws + offP);
    const bool partials = (ws_size >= needP);

    kan_bases<<<(BATCH * INF) / 256, 256, 0, stream>>>(x, (short8*)Abf);
    kan_wconv<<<(OUTF * KDIM / 8) / 256, 256, 0, stream>>>((const f32x4*)w, (short8*)Wbf);

    const int grid = (BATCH / 256) * (OUTF / 256) * KS;     // 256
    if (partials) {
        kan_gemm<<<grid, 1024, 0, stream>>>(Abf, Wbf, P, 0);
        kan_reduce<<<(BATCH * OUTF / 4) / 256, 256, 0, stream>>>((const f32x4*)P, (f32x4*)out);
    } else {
        hipMemsetAsync(out, 0, (size_t)BATCH * OUTF * sizeof(float), stream);
        kan_gemm<<<grid, 1024, 0, stream>>>(Abf, Wbf, out, 1);
    }
}

// Round 9
// 112.348 us; speedup vs baseline: 1.1736x; 1.0724x over previous
//
#include <hip/hip_runtime.h>
#include <hip/hip_bf16.h>
#include <stdint.h>
#include <stddef.h>

#define BATCH 4096
#define INF   1024
#define OUTF  1024
#define KDIM  8192            // 1024 in-features * 8 spline bases
#define KS    4               // split-K factor
#define KSL   (KDIM / KS)     // 2048 per slice
#define BK    64
#define NT    (KSL / BK)      // 32 K-tiles per block

typedef __attribute__((ext_vector_type(8)))  short  short8;
typedef __attribute__((ext_vector_type(4)))  float  f32x4;
typedef __attribute__((ext_vector_type(16))) float  f32x16;

__device__ constexpr float knot(int j) { return (float)(j - 3) * 0.4f - 1.0f; }

// ---------------------------------------------------------------------------
// Kernel 1: B-spline bases. One thread per (b,i); writes 8 bf16 (16 B).
// ---------------------------------------------------------------------------
__global__ __launch_bounds__(256) void kan_bases(const float* __restrict__ x,
                                                 short8* __restrict__ A) {
    size_t idx = (size_t)blockIdx.x * 256 + threadIdx.x;
    float xv = x[idx];

    float b[11];
#pragma unroll
    for (int j = 0; j < 11; ++j)
        b[j] = (xv >= knot(j) && xv < knot(j + 1)) ? 1.0f : 0.0f;

#pragma unroll
    for (int k = 1; k <= 3; ++k) {
#pragma unroll
        for (int j = 0; j + k < 11; ++j) {
            float left  = (xv - knot(j))         * (1.0f / (knot(j + k)     - knot(j)));
            float right = (knot(j + k + 1) - xv) * (1.0f / (knot(j + k + 1) - knot(j + 1)));
            b[j] = left * b[j] + right * b[j + 1];
        }
    }

    union { short8 v; unsigned short u[8]; } pk;
#pragma unroll
    for (int g = 0; g < 8; ++g) {
        __hip_bfloat16 h = __float2bfloat16(b[g]);
        pk.u[g] = *reinterpret_cast<unsigned short*>(&h);
    }
    A[idx] = pk.v;
}

// ---------------------------------------------------------------------------
// Kernel 2: weight fp32 -> bf16 (B^T row-major over k = i*8+g already).
// ---------------------------------------------------------------------------
__global__ __launch_bounds__(256) void kan_wconv(const f32x4* __restrict__ w,
                                                 short8* __restrict__ Wb) {
    size_t idx = (size_t)blockIdx.x * 256 + threadIdx.x;
    f32x4 a = w[idx * 2];
    f32x4 c = w[idx * 2 + 1];
    float t[8] = {a[0], a[1], a[2], a[3], c[0], c[1], c[2], c[3]};
    union { short8 v; unsigned short u[8]; } pk;
#pragma unroll
    for (int g = 0; g < 8; ++g) {
        __hip_bfloat16 h = __float2bfloat16(t[g]);
        pk.u[g] = *reinterpret_cast<unsigned short*>(&h);
    }
    Wb[idx] = pk.v;
}

// ---------------------------------------------------------------------------
// Kernel 3: bf16 GEMM, 256x256 tile, BK=64, split-K=4, double-buffer (128 KiB).
// 1024 threads = 16 waves (4M x 4N, 64x64 per wave), mfma_f32_32x32x16_bf16.
// Epoch = one BK=64 tile: 16 ds_read + 16 MFMA per wave between barriers
// (compiler pipelines kq steps via counted lgkmcnt). Distance-1 prefetch;
// vmcnt(0)+barrier once per epoch (loads issued a full epoch earlier).
// 8-slot XOR swizzle at 128-B rows: phys = k8 ^ (row&7) -> banks 4*phys,
// uniform 8/bank (r6-measured ZERO conflicts). Both-sides involution:
// staged source col pre-swizzled, read col swizzled.
// mode 0: split-K partials to P; mode 1: atomicAdd into pre-zeroed C.
// ---------------------------------------------------------------------------
__device__ __forceinline__ void gload16(const void* g, void* l) {
    __builtin_amdgcn_global_load_lds((const __attribute__((address_space(1))) void*)g,
                                     (__attribute__((address_space(3))) void*)l,
                                     16, 0, 0);
}

#define MFMA32(a, b, c) __builtin_amdgcn_mfma_f32_32x32x16_bf16((a), (b), (c), 0, 0, 0)

__global__ __launch_bounds__(1024, 1) void kan_gemm(const __hip_bfloat16* __restrict__ A,
                                                    const __hip_bfloat16* __restrict__ Bt,
                                                    float* __restrict__ out,
                                                    int mode) {
    __shared__ __hip_bfloat16 sA[2][256 * 64];   // 64 KiB
    __shared__ __hip_bfloat16 sB[2][256 * 64];   // 64 KiB

    const int tid  = threadIdx.x;
    const int orig = blockIdx.x;
    const int sb   = (orig & 7) * 32 + (orig >> 3);   // XCD chunk swizzle (256%8==0)
    const int bm   = sb >> 4;            // 0..15
    const int bn   = (sb >> 2) & 3;      // 0..3
    const int ks   = sb & 3;             // 0..3
    const int m0   = bm << 8;
    const int n0   = bn << 8;
    const int k0   = ks * KSL;

    // staging: thread t -> rows (t>>3)+r*128, 16B slot (t&7); LDS dest linear
    // (elem t*8 + r*8192). Source col pre-swizzled: LDS[row][s]=G[row][s^(row&7)],
    // (row&7) == ((t>>3)&7) for both r-steps (128 = 0 mod 8).
    const int srow = tid >> 3;                                // 0..127
    const int scol = (((tid & 7) ^ (srow & 7)) << 3);         // elems
    const __hip_bfloat16* gA = A  + (size_t)(m0 + srow) * KDIM + k0 + scol;
    const __hip_bfloat16* gB = Bt + (size_t)(n0 + srow) * KDIM + k0 + scol;
    const int t8 = tid * 8;

#define GLA(buf, kt, r) gload16(gA + (size_t)(kt) * BK + (size_t)((r) * 128) * KDIM, \
                                &sA[buf][(r) * 8192 + t8])
#define GLB(buf, kt, r) gload16(gB + (size_t)(kt) * BK + (size_t)((r) * 128) * KDIM, \
                                &sB[buf][(r) * 8192 + t8])

    // compute: wave w -> rows [(w>>2)*64,+64), cols [(w&3)*64,+64)
    const int w    = tid >> 6;
    const int lane = tid & 63;
    const int wr   = w >> 2;             // 0..3
    const int wc   = w & 3;              // 0..3
    const int l31  = lane & 31;
    const int l5   = lane >> 5;          // 0..1
    const int ar0  = (wr << 6) + l31;    // + fi*32
    const int br0  = (wc << 6) + l31;    // + fj*32
    const int rx   = l31 & 7;            // read-side XOR (row&7)

    f32x16 acc00 = {}, acc01 = {}, acc10 = {}, acc11 = {};

    // --- prologue: stage tile 0 into buf0; drain; barrier ---
    GLA(0, 0, 0); GLA(0, 0, 1); GLB(0, 0, 0); GLB(0, 0, 1);
    asm volatile("s_waitcnt vmcnt(0)" ::: "memory");
    __builtin_amdgcn_s_barrier();

#pragma unroll 1
    for (int t = 0; t < NT; ++t) {
        const int buf = t & 1;
        const __hip_bfloat16* tA = &sA[buf][0];
        const __hip_bfloat16* tB = &sB[buf][0];

        // prefetch tile t+1 into the other buffer (issued a full epoch early)
        if (t + 1 < NT) {
            GLA(buf ^ 1, t + 1, 0); GLA(buf ^ 1, t + 1, 1);
            GLB(buf ^ 1, t + 1, 0); GLB(buf ^ 1, t + 1, 1);
        }
        __builtin_amdgcn_sched_barrier(0);   // pin prefetch issue at epoch top

        // epoch body: 4 kq steps; per step 4 ds_read_b128 + 4 MFMA(32x32x16).
        // k-slot8 = kq*2 + l5, phys = slot8 ^ (row&7) -> conflict-free banks.
#pragma unroll
        for (int kq = 0; kq < 4; ++kq) {
            const int ph = (((kq << 1) | l5) ^ rx) << 3;   // elem offset in row
            short8 a0 = *reinterpret_cast<const short8*>(tA + (ar0     ) * BK + ph);
            short8 a1 = *reinterpret_cast<const short8*>(tA + (ar0 + 32) * BK + ph);
            short8 b0 = *reinterpret_cast<const short8*>(tB + (br0     ) * BK + ph);
            short8 b1 = *reinterpret_cast<const short8*>(tB + (br0 + 32) * BK + ph);
            acc00 = MFMA32(a0, b0, acc00);
            acc01 = MFMA32(a0, b1, acc01);
            acc10 = MFMA32(a1, b0, acc10);
            acc11 = MFMA32(a1, b1, acc11);
        }

        // --- epoch boundary: all staging landed (issued ~4000 cy ago) ---
        asm volatile("s_waitcnt vmcnt(0)" ::: "memory");
        __builtin_amdgcn_s_barrier();
    }
#undef GLA
#undef GLB

    // --- epilogue: 32x32 C/D layout: col = lane&31,
    //     row = (reg&3) + 8*(reg>>2) + 4*(lane>>5)  [m74/m101] ---
#define STORE_FRAG(accv, fi, fj)                                               \
    _Pragma("unroll")                                                          \
    for (int r = 0; r < 16; ++r) {                                             \
        int row = m0 + (wr << 6) + (fi) * 32 + (r & 3) + 8 * (r >> 2) + 4 * l5;\
        int col = n0 + (wc << 6) + (fj) * 32 + l31;                            \
        dst[(size_t)row * OUTF + col] = accv[r];                               \
    }
#define ATOM_FRAG(accv, fi, fj)                                                \
    _Pragma("unroll")                                                          \
    for (int r = 0; r < 16; ++r) {                                             \
        int row = m0 + (wr << 6) + (fi) * 32 + (r & 3) + 8 * (r >> 2) + 4 * l5;\
        int col = n0 + (wc << 6) + (fj) * 32 + l31;                            \
        atomicAdd(&out[(size_t)row * OUTF + col], accv[r]);                    \
    }

    if (mode == 0) {
        float* dst = out + (size_t)ks * BATCH * OUTF;
        STORE_FRAG(acc00, 0, 0);
        STORE_FRAG(acc01, 0, 1);
        STORE_FRAG(acc10, 1, 0);
        STORE_FRAG(acc11, 1, 1);
    } else {
        ATOM_FRAG(acc00, 0, 0);
        ATOM_FRAG(acc01, 0, 1);
        ATOM_FRAG(acc10, 1, 0);
        ATOM_FRAG(acc11, 1, 1);
    }
#undef STORE_FRAG
#undef ATOM_FRAG
}

// ---------------------------------------------------------------------------
// Kernel 4: split-K reduce  out = P0 + P1 + P2 + P3
// ---------------------------------------------------------------------------
__global__ __launch_bounds__(256) void kan_reduce(const f32x4* __restrict__ P,
                                                  f32x4* __restrict__ out) {
    size_t i = (size_t)blockIdx.x * 256 + threadIdx.x;   // 1M f32x4
    const size_t stride = (size_t)BATCH * OUTF / 4;
    out[i] = ((P[i] + P[i + stride]) + (P[i + 2 * stride] + P[i + 3 * stride]));
}

// ---------------------------------------------------------------------------
extern "C" void kernel_launch(void* const* d_in, const int* in_sizes, int n_in,
                              void* d_out, int out_size, void* d_ws, size_t ws_size,
                              hipStream_t stream) {
    const float* x = (const float*)d_in[0];       // (4096, 1024) fp32
    const float* w = (const float*)d_in[1];       // (1024, 1024, 8) fp32
    float* out = (float*)d_out;                   // (4096, 1024) fp32

    const size_t offW  = (size_t)BATCH * KDIM * 2;           // Abf: 64 MiB
    const size_t offP  = offW + (size_t)OUTF * KDIM * 2;     // Wbf: +16 MiB
    const size_t needP = offP + (size_t)KS * BATCH * OUTF * sizeof(float); // +64 MiB

    __hip_bfloat16* Abf = (__hip_bfloat16*)d_ws;
    __hip_bfloat16* Wbf = (__hip_bfloat16*)((char*)d_ws + offW);
    float*          P   = (float*)((char*)d_ws + offP);
    const bool partials = (ws_size >= needP);

    kan_bases<<<(BATCH * INF) / 256, 256, 0, stream>>>(x, (short8*)Abf);
    kan_wconv<<<(OUTF * KDIM / 8) / 256, 256, 0, stream>>>((const f32x4*)w, (short8*)Wbf);

    const int grid = (BATCH / 256) * (OUTF / 256) * KS;     // 256
    if (partials) {
        kan_gemm<<<grid, 1024, 0, stream>>>(Abf, Wbf, P, 0);
        kan_reduce<<<(BATCH * OUTF / 4) / 256, 256, 0, stream>>>((const f32x4*)P, (f32x4*)out);
    } else {
        hipMemsetAsync(out, 0, (size_t)BATCH * OUTF * sizeof(float), stream);
        kan_gemm<<<grid, 1024, 0, stream>>>(Abf, Wbf, out, 1);
    }
}

// Round 10
// 104.254 us; speedup vs baseline: 1.2648x; 1.0776x over previous
//
#include <hip/hip_runtime.h>
#include <hip/hip_bf16.h>
#include <stdint.h>
#include <stddef.h>

#define BATCH 4096
#define INF   1024
#define OUTF  1024
#define KDIM  8192            // 1024 in-features * 8 spline bases
#define KS    4               // split-K factor
#define KSL   (KDIM / KS)     // 2048 per slice
#define BK    64
#define NT    (KSL / BK)      // 32 K-tiles per block

typedef __attribute__((ext_vector_type(8)))  short  short8;
typedef __attribute__((ext_vector_type(4)))  float  f32x4;

__device__ constexpr float knot(int j) { return (float)(j - 3) * 0.4f - 1.0f; }

// ---------------------------------------------------------------------------
// Kernel 1: B-spline bases. One thread per (b,i); writes 8 bf16 (16 B).
// ---------------------------------------------------------------------------
__global__ __launch_bounds__(256) void kan_bases(const float* __restrict__ x,
                                                 short8* __restrict__ A) {
    size_t idx = (size_t)blockIdx.x * 256 + threadIdx.x;
    float xv = x[idx];

    float b[11];
#pragma unroll
    for (int j = 0; j < 11; ++j)
        b[j] = (xv >= knot(j) && xv < knot(j + 1)) ? 1.0f : 0.0f;

#pragma unroll
    for (int k = 1; k <= 3; ++k) {
#pragma unroll
        for (int j = 0; j + k < 11; ++j) {
            float left  = (xv - knot(j))         * (1.0f / (knot(j + k)     - knot(j)));
            float right = (knot(j + k + 1) - xv) * (1.0f / (knot(j + k + 1) - knot(j + 1)));
            b[j] = left * b[j] + right * b[j + 1];
        }
    }

    union { short8 v; unsigned short u[8]; } pk;
#pragma unroll
    for (int g = 0; g < 8; ++g) {
        __hip_bfloat16 h = __float2bfloat16(b[g]);
        pk.u[g] = *reinterpret_cast<unsigned short*>(&h);
    }
    A[idx] = pk.v;
}

// ---------------------------------------------------------------------------
// Kernel 2: weight fp32 -> bf16 (B^T row-major over k = i*8+g already).
// ---------------------------------------------------------------------------
__global__ __launch_bounds__(256) void kan_wconv(const f32x4* __restrict__ w,
                                                 short8* __restrict__ Wb) {
    size_t idx = (size_t)blockIdx.x * 256 + threadIdx.x;
    f32x4 a = w[idx * 2];
    f32x4 c = w[idx * 2 + 1];
    float t[8] = {a[0], a[1], a[2], a[3], c[0], c[1], c[2], c[3]};
    union { short8 v; unsigned short u[8]; } pk;
#pragma unroll
    for (int g = 0; g < 8; ++g) {
        __hip_bfloat16 h = __float2bfloat16(t[g]);
        pk.u[g] = *reinterpret_cast<unsigned short*>(&h);
    }
    Wb[idx] = pk.v;
}

// ---------------------------------------------------------------------------
// Kernel 3: bf16 GEMM, 256x256 tile, BK=64, split-K=4, double-buffer (128 KiB).
// 1024 threads = 16 waves (4M x 4N, 64x64 per wave), mfma_f32_16x16x32_bf16
// with r6's VERIFIED-ZERO-CONFLICT fragment pattern (lr/lk addressing,
// phys = (4kk+lk) ^ (lr&7) on 8-slot XOR-swizzled 128-B rows).
// Distance-1 prefetch; one vmcnt(0)+barrier per K-tile (loads issued a full
// epoch early). mode 0: split-K partials; mode 1: atomicAdd fallback.
// ---------------------------------------------------------------------------
__device__ __forceinline__ void gload16(const void* g, void* l) {
    __builtin_amdgcn_global_load_lds((const __attribute__((address_space(1))) void*)g,
                                     (__attribute__((address_space(3))) void*)l,
                                     16, 0, 0);
}

#define MFMA(a, b, c) __builtin_amdgcn_mfma_f32_16x16x32_bf16((a), (b), (c), 0, 0, 0)

__global__ __launch_bounds__(1024, 1) void kan_gemm(const __hip_bfloat16* __restrict__ A,
                                                    const __hip_bfloat16* __restrict__ Bt,
                                                    float* __restrict__ out,
                                                    int mode) {
    __shared__ __hip_bfloat16 sA[2][256 * 64];   // 64 KiB
    __shared__ __hip_bfloat16 sB[2][256 * 64];   // 64 KiB

    const int tid  = threadIdx.x;
    const int orig = blockIdx.x;
    const int sb   = (orig & 7) * 32 + (orig >> 3);   // XCD chunk swizzle (256%8==0)
    const int bm   = sb >> 4;            // 0..15
    const int bn   = (sb >> 2) & 3;      // 0..3
    const int ks   = sb & 3;             // 0..3
    const int m0   = bm << 8;
    const int n0   = bn << 8;
    const int k0   = ks * KSL;

    // staging: thread t -> rows (t>>3)+r*128, 16B slot (t&7); LDS dest linear.
    // Source col pre-swizzled: LDS[row][s] = G[row][s ^ (row&7)].
    const int srow = tid >> 3;                                // 0..127
    const int scol = (((tid & 7) ^ (srow & 7)) << 3);         // elems
    const __hip_bfloat16* gA = A  + (size_t)(m0 + srow) * KDIM + k0 + scol;
    const __hip_bfloat16* gB = Bt + (size_t)(n0 + srow) * KDIM + k0 + scol;
    const int t8 = tid * 8;

#define GLA(buf, kt, r) gload16(gA + (size_t)(kt) * BK + (size_t)((r) * 128) * KDIM, \
                                &sA[buf][(r) * 8192 + t8])
#define GLB(buf, kt, r) gload16(gB + (size_t)(kt) * BK + (size_t)((r) * 128) * KDIM, \
                                &sB[buf][(r) * 8192 + t8])

    // compute: wave w -> rows [(w>>2)*64,+64), cols [(w&3)*64,+64)
    const int w    = tid >> 6;
    const int lane = tid & 63;
    const int wr   = w >> 2;             // 0..3
    const int wc   = w & 3;              // 0..3
    const int lr   = lane & 15;
    const int lk   = lane >> 4;          // 0..3
    const int ar0  = (wr << 6) + lr;     // + fi*16
    const int br0  = (wc << 6) + lr;     // + fj*16
    const int rx   = lr & 7;             // read-side XOR (row&7)

    f32x4 acc[4][4];
#pragma unroll
    for (int i = 0; i < 4; ++i)
#pragma unroll
        for (int j = 0; j < 4; ++j)
            acc[i][j] = (f32x4){0.0f, 0.0f, 0.0f, 0.0f};

    // --- prologue: stage tile 0 into buf0; drain; barrier ---
    GLA(0, 0, 0); GLA(0, 0, 1); GLB(0, 0, 0); GLB(0, 0, 1);
    asm volatile("s_waitcnt vmcnt(0)" ::: "memory");
    __builtin_amdgcn_s_barrier();

#pragma unroll 1
    for (int t = 0; t < NT; ++t) {
        const int buf = t & 1;
        const __hip_bfloat16* tA = &sA[buf][0];
        const __hip_bfloat16* tB = &sB[buf][0];

        // prefetch tile t+1 into the other buffer (issued a full epoch early)
        if (t + 1 < NT) {
            GLA(buf ^ 1, t + 1, 0); GLA(buf ^ 1, t + 1, 1);
            GLB(buf ^ 1, t + 1, 0); GLB(buf ^ 1, t + 1, 1);
        }
        __builtin_amdgcn_sched_barrier(0);   // pin prefetch issue at epoch top

        // epoch body (r6 pattern): 2 kk steps; per step 8 ds_read_b128 +
        // 16 MFMA(16x16x32). phys slot = (4kk+lk) ^ (lr&7) -> 0 conflicts (r6).
#pragma unroll
        for (int kk = 0; kk < 2; ++kk) {
            const int ph = (((kk << 2) | lk) ^ rx) << 3;   // elem offset in row
            short8 af[4], bf[4];
#pragma unroll
            for (int fi = 0; fi < 4; ++fi)
                af[fi] = *reinterpret_cast<const short8*>(tA + (ar0 + fi * 16) * BK + ph);
#pragma unroll
            for (int fj = 0; fj < 4; ++fj)
                bf[fj] = *reinterpret_cast<const short8*>(tB + (br0 + fj * 16) * BK + ph);
#pragma unroll
            for (int fi = 0; fi < 4; ++fi)
#pragma unroll
                for (int fj = 0; fj < 4; ++fj)
                    acc[fi][fj] = MFMA(af[fi], bf[fj], acc[fi][fj]);
        }

        // --- epoch boundary: all staging landed (issued ~2500 cy ago) ---
        asm volatile("s_waitcnt vmcnt(0)" ::: "memory");
        __builtin_amdgcn_s_barrier();
    }
#undef GLA
#undef GLB

    // --- epilogue: 16x16 C/D layout: col = lane&15, row = (lane>>4)*4 + reg ---
    if (mode == 0) {
        float* dst = out + (size_t)ks * BATCH * OUTF;
#pragma unroll
        for (int fi = 0; fi < 4; ++fi) {
#pragma unroll
            for (int fj = 0; fj < 4; ++fj) {
                float* cp = dst + (size_t)(m0 + (wr << 6) + fi * 16 + lk * 4) * OUTF
                               + (n0 + (wc << 6) + fj * 16 + lr);
#pragma unroll
                for (int r = 0; r < 4; ++r)
                    cp[(size_t)r * OUTF] = acc[fi][fj][r];
            }
        }
    } else {
#pragma unroll
        for (int fi = 0; fi < 4; ++fi) {
#pragma unroll
            for (int fj = 0; fj < 4; ++fj) {
                float* cp = out + (size_t)(m0 + (wr << 6) + fi * 16 + lk * 4) * OUTF
                               + (n0 + (wc << 6) + fj * 16 + lr);
#pragma unroll
                for (int r = 0; r < 4; ++r)
                    atomicAdd(cp + (size_t)r * OUTF, acc[fi][fj][r]);
            }
        }
    }
}

// ---------------------------------------------------------------------------
// Kernel 4: split-K reduce  out = P0 + P1 + P2 + P3
// ---------------------------------------------------------------------------
__global__ __launch_bounds__(256) void kan_reduce(const f32x4* __restrict__ P,
                                                  f32x4* __restrict__ out) {
    size_t i = (size_t)blockIdx.x * 256 + threadIdx.x;   // 1M f32x4
    const size_t stride = (size_t)BATCH * OUTF / 4;
    out[i] = ((P[i] + P[i + stride]) + (P[i + 2 * stride] + P[i + 3 * stride]));
}

// ---------------------------------------------------------------------------
extern "C" void kernel_launch(void* const* d_in, const int* in_sizes, int n_in,
                              void* d_out, int out_size, void* d_ws, size_t ws_size,
                              hipStream_t stream) {
    const float* x = (const float*)d_in[0];       // (4096, 1024) fp32
    const float* w = (const float*)d_in[1];       // (1024, 1024, 8) fp32
    float* out = (float*)d_out;                   // (4096, 1024) fp32

    const size_t offW  = (size_t)BATCH * KDIM * 2;           // Abf: 64 MiB
    const size_t offP  = offW + (size_t)OUTF * KDIM * 2;     // Wbf: +16 MiB
    const size_t needP = offP + (size_t)KS * BATCH * OUTF * sizeof(float); // +64 MiB

    __hip_bfloat16* Abf = (__hip_bfloat16*)d_ws;
    __hip_bfloat16* Wbf = (__hip_bfloat16*)((char*)d_ws + offW);
    float*          P   = (float*)((char*)d_ws + offP);
    const bool partials = (ws_size >= needP);

    kan_bases<<<(BATCH * INF) / 256, 256, 0, stream>>>(x, (short8*)Abf);
    kan_wconv<<<(OUTF * KDIM / 8) / 256, 256, 0, stream>>>((const f32x4*)w, (short8*)Wbf);

    const int grid = (BATCH / 256) * (OUTF / 256) * KS;     // 256
    if (partials) {
        kan_gemm<<<grid, 1024, 0, stream>>>(Abf, Wbf, P, 0);
        kan_reduce<<<(BATCH * OUTF / 4) / 256, 256, 0, stream>>>((const f32x4*)P, (f32x4*)out);
    } else {
        hipMemsetAsync(out, 0, (size_t)BATCH * OUTF * sizeof(float), stream);
        kan_gemm<<<grid, 1024, 0, stream>>>(Abf, Wbf, out, 1);
    }
}

// Round 11
// 96.885 us; speedup vs baseline: 1.3609x; 1.0761x over previous
//
#include <hip/hip_runtime.h>
#include <hip/hip_bf16.h>
#include <stdint.h>
#include <stddef.h>

#define BATCH 4096
#define INF   1024
#define OUTF  1024
#define KDIM  8192            // 1024 in-features * 8 spline bases
#define KS    4               // split-K factor
#define KSL   (KDIM / KS)     // 2048 per slice
#define BK    64
#define NT    (KSL / BK)      // 32 K-tiles per block

typedef __attribute__((ext_vector_type(8)))  short           short8;
typedef __attribute__((ext_vector_type(8)))  unsigned short  ushort8;
typedef __attribute__((ext_vector_type(4)))  float           f32x4;

__device__ constexpr float knot(int j) { return (float)(j - 3) * 0.4f - 1.0f; }

// ---------------------------------------------------------------------------
// Kernel 1: fused prep. Blocks [0,16384): B-spline bases (one thread per
// (b,i), 8 bf16 out). Blocks [16384,20480): weight fp32 -> bf16.
// ---------------------------------------------------------------------------
__global__ __launch_bounds__(256) void kan_prep(const float* __restrict__ x,
                                                short8* __restrict__ A,
                                                const f32x4* __restrict__ w,
                                                short8* __restrict__ Wb) {
    const int blk = blockIdx.x;
    if (blk < (BATCH * INF) / 256) {
        size_t idx = (size_t)blk * 256 + threadIdx.x;
        float xv = x[idx];

        float b[11];
#pragma unroll
        for (int j = 0; j < 11; ++j)
            b[j] = (xv >= knot(j) && xv < knot(j + 1)) ? 1.0f : 0.0f;

#pragma unroll
        for (int k = 1; k <= 3; ++k) {
#pragma unroll
            for (int j = 0; j + k < 11; ++j) {
                float left  = (xv - knot(j))         * (1.0f / (knot(j + k)     - knot(j)));
                float right = (knot(j + k + 1) - xv) * (1.0f / (knot(j + k + 1) - knot(j + 1)));
                b[j] = left * b[j] + right * b[j + 1];
            }
        }

        union { short8 v; unsigned short u[8]; } pk;
#pragma unroll
        for (int g = 0; g < 8; ++g) {
            __hip_bfloat16 h = __float2bfloat16(b[g]);
            pk.u[g] = *reinterpret_cast<unsigned short*>(&h);
        }
        A[idx] = pk.v;
    } else {
        size_t idx = (size_t)(blk - (BATCH * INF) / 256) * 256 + threadIdx.x;
        f32x4 a = w[idx * 2];
        f32x4 c = w[idx * 2 + 1];
        float t[8] = {a[0], a[1], a[2], a[3], c[0], c[1], c[2], c[3]};
        union { short8 v; unsigned short u[8]; } pk;
#pragma unroll
        for (int g = 0; g < 8; ++g) {
            __hip_bfloat16 h = __float2bfloat16(t[g]);
            pk.u[g] = *reinterpret_cast<unsigned short*>(&h);
        }
        Wb[idx] = pk.v;
    }
}

// ---------------------------------------------------------------------------
// Kernel 2: bf16 GEMM, 256x256 tile, BK=64, split-K=4, double-buffer (128 KiB).
// 1024 threads = 16 waves (4M x 4N, 64x64 per wave), mfma_f32_16x16x32_bf16
// with the verified-zero-conflict fragment pattern (r10: conflicts == 0).
// Distance-1 prefetch; one vmcnt(0)+barrier per K-tile.
// mode 0: bf16 split-K partials to Pb; mode 1: fp32 atomicAdd fallback.
// ---------------------------------------------------------------------------
__device__ __forceinline__ void gload16(const void* g, void* l) {
    __builtin_amdgcn_global_load_lds((const __attribute__((address_space(1))) void*)g,
                                     (__attribute__((address_space(3))) void*)l,
                                     16, 0, 0);
}

#define MFMA(a, b, c) __builtin_amdgcn_mfma_f32_16x16x32_bf16((a), (b), (c), 0, 0, 0)

__global__ __launch_bounds__(1024, 1) void kan_gemm(const __hip_bfloat16* __restrict__ A,
                                                    const __hip_bfloat16* __restrict__ Bt,
                                                    __hip_bfloat16* __restrict__ Pb,
                                                    float* __restrict__ outC,
                                                    int mode) {
    __shared__ __hip_bfloat16 sA[2][256 * 64];   // 64 KiB
    __shared__ __hip_bfloat16 sB[2][256 * 64];   // 64 KiB

    const int tid  = threadIdx.x;
    const int orig = blockIdx.x;
    const int sb   = (orig & 7) * 32 + (orig >> 3);   // XCD chunk swizzle (256%8==0)
    const int bm   = sb >> 4;            // 0..15
    const int bn   = (sb >> 2) & 3;      // 0..3
    const int ks   = sb & 3;             // 0..3
    const int m0   = bm << 8;
    const int n0   = bn << 8;
    const int k0   = ks * KSL;

    // staging: thread t -> rows (t>>3)+r*128, 16B slot (t&7); LDS dest linear.
    // Source col pre-swizzled: LDS[row][s] = G[row][s ^ (row&7)].
    const int srow = tid >> 3;                                // 0..127
    const int scol = (((tid & 7) ^ (srow & 7)) << 3);         // elems
    const __hip_bfloat16* gA = A  + (size_t)(m0 + srow) * KDIM + k0 + scol;
    const __hip_bfloat16* gB = Bt + (size_t)(n0 + srow) * KDIM + k0 + scol;
    const int t8 = tid * 8;

#define GLA(buf, kt, r) gload16(gA + (size_t)(kt) * BK + (size_t)((r) * 128) * KDIM, \
                                &sA[buf][(r) * 8192 + t8])
#define GLB(buf, kt, r) gload16(gB + (size_t)(kt) * BK + (size_t)((r) * 128) * KDIM, \
                                &sB[buf][(r) * 8192 + t8])

    // compute: wave w -> rows [(w>>2)*64,+64), cols [(w&3)*64,+64)
    const int w    = tid >> 6;
    const int lane = tid & 63;
    const int wr   = w >> 2;             // 0..3
    const int wc   = w & 3;              // 0..3
    const int lr   = lane & 15;
    const int lk   = lane >> 4;          // 0..3
    const int ar0  = (wr << 6) + lr;     // + fi*16
    const int br0  = (wc << 6) + lr;     // + fj*16
    const int rx   = lr & 7;             // read-side XOR (row&7)

    f32x4 acc[4][4];
#pragma unroll
    for (int i = 0; i < 4; ++i)
#pragma unroll
        for (int j = 0; j < 4; ++j)
            acc[i][j] = (f32x4){0.0f, 0.0f, 0.0f, 0.0f};

    // --- prologue: stage tile 0 into buf0; drain; barrier ---
    GLA(0, 0, 0); GLA(0, 0, 1); GLB(0, 0, 0); GLB(0, 0, 1);
    asm volatile("s_waitcnt vmcnt(0)" ::: "memory");
    __builtin_amdgcn_s_barrier();

#pragma unroll 1
    for (int t = 0; t < NT; ++t) {
        const int buf = t & 1;
        const __hip_bfloat16* tA = &sA[buf][0];
        const __hip_bfloat16* tB = &sB[buf][0];

        // prefetch tile t+1 into the other buffer (issued a full epoch early)
        if (t + 1 < NT) {
            GLA(buf ^ 1, t + 1, 0); GLA(buf ^ 1, t + 1, 1);
            GLB(buf ^ 1, t + 1, 0); GLB(buf ^ 1, t + 1, 1);
        }
        __builtin_amdgcn_sched_barrier(0);   // pin prefetch issue at epoch top

        // epoch body: 2 kk steps; per step 8 ds_read_b128 + 16 MFMA(16x16x32).
        // phys slot = (4kk+lk) ^ (lr&7) -> 0 conflicts (r10-measured).
#pragma unroll
        for (int kk = 0; kk < 2; ++kk) {
            const int ph = (((kk << 2) | lk) ^ rx) << 3;   // elem offset in row
            short8 af[4], bf[4];
#pragma unroll
            for (int fi = 0; fi < 4; ++fi)
                af[fi] = *reinterpret_cast<const short8*>(tA + (ar0 + fi * 16) * BK + ph);
#pragma unroll
            for (int fj = 0; fj < 4; ++fj)
                bf[fj] = *reinterpret_cast<const short8*>(tB + (br0 + fj * 16) * BK + ph);
#pragma unroll
            for (int fi = 0; fi < 4; ++fi)
#pragma unroll
                for (int fj = 0; fj < 4; ++fj)
                    acc[fi][fj] = MFMA(af[fi], bf[fj], acc[fi][fj]);
        }

        // --- epoch boundary: all staging landed (issued ~2500 cy ago) ---
        asm volatile("s_waitcnt vmcnt(0)" ::: "memory");
        __builtin_amdgcn_s_barrier();
    }
#undef GLA
#undef GLB

    // --- epilogue: 16x16 C/D layout: col = lane&15, row = (lane>>4)*4 + reg ---
    if (mode == 0) {
        // bf16 split-K partials (halves epilogue + reduce traffic)
        __hip_bfloat16* dst = Pb + (size_t)ks * BATCH * OUTF;
#pragma unroll
        for (int fi = 0; fi < 4; ++fi) {
#pragma unroll
            for (int fj = 0; fj < 4; ++fj) {
                __hip_bfloat16* cp = dst
                    + (size_t)(m0 + (wr << 6) + fi * 16 + lk * 4) * OUTF
                    + (n0 + (wc << 6) + fj * 16 + lr);
#pragma unroll
                for (int r = 0; r < 4; ++r)
                    cp[(size_t)r * OUTF] = __float2bfloat16(acc[fi][fj][r]);
            }
        }
    } else {
#pragma unroll
        for (int fi = 0; fi < 4; ++fi) {
#pragma unroll
            for (int fj = 0; fj < 4; ++fj) {
                float* cp = outC + (size_t)(m0 + (wr << 6) + fi * 16 + lk * 4) * OUTF
                                 + (n0 + (wc << 6) + fj * 16 + lr);
#pragma unroll
                for (int r = 0; r < 4; ++r)
                    atomicAdd(cp + (size_t)r * OUTF, acc[fi][fj][r]);
            }
        }
    }
}

// ---------------------------------------------------------------------------
// Kernel 3: split-K reduce  out = sum of 4 bf16 partials (fp32 accumulate).
// 8 elems per thread: 4x ushort8 reads (16B), 2x f32x4 writes.
// ---------------------------------------------------------------------------
__global__ __launch_bounds__(256) void kan_reduce(const ushort8* __restrict__ Pb,
                                                  f32x4* __restrict__ out) {
    size_t i = (size_t)blockIdx.x * 256 + threadIdx.x;   // per 8 elems
    const size_t stride = (size_t)BATCH * OUTF / 8;
    ushort8 p0 = Pb[i];
    ushort8 p1 = Pb[i + stride];
    ushort8 p2 = Pb[i + 2 * stride];
    ushort8 p3 = Pb[i + 3 * stride];

    f32x4 lo, hi;
#pragma unroll
    for (int e = 0; e < 8; ++e) {
        union { unsigned int u; float f; } c0, c1, c2, c3;
        c0.u = (unsigned int)p0[e] << 16;
        c1.u = (unsigned int)p1[e] << 16;
        c2.u = (unsigned int)p2[e] << 16;
        c3.u = (unsigned int)p3[e] << 16;
        float s = (c0.f + c1.f) + (c2.f + c3.f);
        if (e < 4) lo[e] = s; else hi[e - 4] = s;
    }
    out[i * 2]     = lo;
    out[i * 2 + 1] = hi;
}

// ---------------------------------------------------------------------------
extern "C" void kernel_launch(void* const* d_in, const int* in_sizes, int n_in,
                              void* d_out, int out_size, void* d_ws, size_t ws_size,
                              hipStream_t stream) {
    const float* x = (const float*)d_in[0];       // (4096, 1024) fp32
    const float* w = (const float*)d_in[1];       // (1024, 1024, 8) fp32
    float* out = (float*)d_out;                   // (4096, 1024) fp32

    const size_t offW  = (size_t)BATCH * KDIM * 2;           // Abf: 64 MiB
    const size_t offP  = offW + (size_t)OUTF * KDIM * 2;     // Wbf: +16 MiB
    const size_t needP = offP + (size_t)KS * BATCH * OUTF * 2; // +32 MiB bf16 partials

    __hip_bfloat16* Abf = (__hip_bfloat16*)d_ws;
    __hip_bfloat16* Wbf = (__hip_bfloat16*)((char*)d_ws + offW);
    __hip_bfloat16* Pb  = (__hip_bfloat16*)((char*)d_ws + offP);
    const bool partials = (ws_size >= needP);

    const int prepGrid = (BATCH * INF) / 256 + (OUTF * KDIM / 8) / 256;  // 20480
    kan_prep<<<prepGrid, 256, 0, stream>>>(x, (short8*)Abf, (const f32x4*)w, (short8*)Wbf);

    const int grid = (BATCH / 256) * (OUTF / 256) * KS;     // 256
    if (partials) {
        kan_gemm<<<grid, 1024, 0, stream>>>(Abf, Wbf, Pb, out, 0);
        kan_reduce<<<(BATCH * OUTF / 8) / 256, 256, 0, stream>>>((const ushort8*)Pb, (f32x4*)out);
    } else {
        hipMemsetAsync(out, 0, (size_t)BATCH * OUTF * sizeof(float), stream);
        kan_gemm<<<grid, 1024, 0, stream>>>(Abf, Wbf, Pb, out, 1);
    }
}